// Round 9
// baseline (68.194 us; speedup 1.0000x reference)
//
#include <hip/hip_runtime.h>
#include <hip/hip_bf16.h>

#define BS 16
#define CH 256
#define TT 2048
#define NBINS 512   // 16 batches x 32 start-buckets

typedef unsigned short ushortv8 __attribute__((ext_vector_type(8)));
typedef float floatv4 __attribute__((ext_vector_type(4)));   // native vec: OK for nt builtins

// ---------------------------------------------------------------------------
// Sort body: bin ROIs by (batch, start-bucket). 256 threads, one block.
// Within-bin order is atomic-arrival (nondeterministic) but each ROI's output
// is order-independent -> d_out deterministic.
// ---------------------------------------------------------------------------
__device__ void ROIAlign_sort_body(const float* __restrict__ rois, int N,
                                   int* __restrict__ perm, int tid)
{
    __shared__ int hist[NBINS];
    __shared__ int waveSums[4];

    for (int i = tid; i < NBINS; i += 256) hist[i] = 0;
    __syncthreads();

    for (int n = tid; n < N; n += 256) {
        const int   b  = (int)rois[3 * n];
        const float s  = rois[3 * n + 1];
        const int   sb = min(31, max(0, (int)(s * (1.0f / 64.0f))));  // TT/32=64
        atomicAdd(&hist[b * 32 + sb], 1);
    }
    __syncthreads();

    const int a0  = hist[2 * tid];
    const int a1  = hist[2 * tid + 1];
    const int own = a0 + a1;
    int v = own;
    #pragma unroll
    for (int d = 1; d < 64; d <<= 1) {
        int u = __shfl_up(v, d, 64);
        if ((tid & 63) >= d) v += u;
    }
    if ((tid & 63) == 63) waveSums[tid >> 6] = v;
    __syncthreads();
    if (tid == 0) {
        int run = 0;
        #pragma unroll
        for (int i = 0; i < 4; ++i) { int c = waveSums[i]; waveSums[i] = run; run += c; }
    }
    __syncthreads();
    const int excl = v - own + waveSums[tid >> 6];
    hist[2 * tid]     = excl;
    hist[2 * tid + 1] = excl + a0;
    __syncthreads();

    for (int n = tid; n < N; n += 256) {
        const int   b  = (int)rois[3 * n];
        const float s  = rois[3 * n + 1];
        const int   sb = min(31, max(0, (int)(s * (1.0f / 64.0f))));
        const int pos = atomicAdd(&hist[b * 32 + sb], 1);
        perm[pos] = n;
    }
}

// ---------------------------------------------------------------------------
// Transpose (BS, CH, TT) f32 -> (BS, TT+1, CH) bf16 (row TT dups TT-1).
// 64t x 64c tile, floatv4 nt-loads (f32 input read exactly once -> don't
// allocate in L2), ushort8 NORMAL stores (inT seeds L2 for the main kernel).
// LDS tile[64][65]: all phases <=2-way bank-aliased. Sort at blockIdx.z==BS.
// ---------------------------------------------------------------------------
__global__ __launch_bounds__(256) void ROIAlign_transpose_sort_kernel(
    const float* __restrict__ in, __hip_bfloat16* __restrict__ outT,
    const float* __restrict__ rois, int N, int* __restrict__ perm)
{
    const int tid = threadIdx.x;

    if (blockIdx.z == BS) {
        if (blockIdx.x == 0 && blockIdx.y == 0 && perm)
            ROIAlign_sort_body(rois, N, perm, tid);
        return;
    }

    __shared__ float tile[64][65];   // [c][t], odd row stride: <=2-way banks
    const int b  = blockIdx.z;
    const int t0 = blockIdx.x * 64;
    const int c0 = blockIdx.y * 64;

    // read: thread -> c-row r = tid>>2, t-chunk q = tid&3 (16 floats via 4xfloatv4)
    {
        const int r = tid >> 2;
        const int q = tid & 3;
        const float* p = in + ((size_t)(b * CH + c0 + r)) * TT + t0 + q * 16;
        #pragma unroll
        for (int i = 0; i < 4; ++i) {
            const floatv4 f4 = __builtin_nontemporal_load((const floatv4*)(p + 4 * i));
            tile[r][q * 16 + 4 * i + 0] = f4.x;
            tile[r][q * 16 + 4 * i + 1] = f4.y;
            tile[r][q * 16 + 4 * i + 2] = f4.z;
            tile[r][q * 16 + 4 * i + 3] = f4.w;
        }
    }
    __syncthreads();

    // write: thread -> ch-oct o = tid&7, t-row rr = tid>>3 (+32 per pass)
    {
        const int o  = tid & 7;
        const int rr = tid >> 3;
        #pragma unroll
        for (int p2 = 0; p2 < 2; ++p2) {
            const int rp = rr + 32 * p2;
            ushortv8 u;
            #pragma unroll
            for (int k = 0; k < 8; ++k)
                u[k] = __bfloat16_as_ushort(__float2bfloat16(tile[8 * o + k][rp]));
            *(ushortv8*)((unsigned short*)outT +
                ((size_t)b * (TT + 1) + t0 + rp) * CH + c0 + 8 * o) = u;
            if (t0 == TT - 64 && rp == 63) {      // pad row TT = dup of TT-1
                *(ushortv8*)((unsigned short*)outT +
                    ((size_t)b * (TT + 1) + TT) * CH + c0 + 8 * o) = u;
            }
        }
    }
}

// ---------------------------------------------------------------------------
// Main kernel, fd==32, ratio==2 fast path, bf16 gather rows (512B each).
// Thread (wave w, half, lane lc) owns bins f = 4*qf+g, qf = w + 4*half,
// channels 8lc..8lc+7. Two-phase 16KB LDS transpose epilogue, then
// NON-TEMPORAL floatv4 stores: output is write-once, streaming it past L2
// stops the 134MB write stream from evicting the ~2MB/XCD sorted inT chunk
// the gathers depend on (suspected R5-R7 residual bottleneck).
// ---------------------------------------------------------------------------
__global__ __launch_bounds__(256) void ROIAlign_fd32_kernel(
    const __hip_bfloat16* __restrict__ inT,   // (BS, TT+1, CH) bf16
    const float* __restrict__ rois,           // (N, 3)
    const int*   __restrict__ ratio_p,
    const int*   __restrict__ perm,           // may be null
    float*       __restrict__ out)            // (N, CH, 32) f32
{
    __shared__ floatv4 buf[128][8];           // 16 KB

    int m;
    if (perm) {
        const int chunk = gridDim.x >> 3;     // XCD-contiguous mapping
        const int sidx  = (blockIdx.x & 7) * chunk + (blockIdx.x >> 3);
        m = perm[sidx];
    } else {
        m = blockIdx.x;
    }
    const int tid = threadIdx.x;

    const int   b      = (int)rois[3 * m + 0];
    const float bstart = rois[3 * m + 1];
    const float bend   = rois[3 * m + 2];
    const float roi_len = fmaxf(bend - bstart, 1.0f);
    const float binsz   = roi_len * (1.0f / 32.0f);
    const int   ratio   = ratio_p[0];

    if (ratio == 2) {
        const int w    = tid >> 6;            // wave
        const int l    = tid & 63;
        const int half = l >> 5;              // qf = w + 4*half
        const int lc   = l & 31;              // channels 8lc..8lc+7

        const unsigned short* base =
            (const unsigned short*)inT + (size_t)b * (TT + 1) * CH + 8 * lc;

        float acc[4][8];
        #pragma unroll
        for (int g = 0; g < 4; ++g)
            #pragma unroll
            for (int j = 0; j < 8; ++j) acc[g][j] = 0.0f;

        #pragma unroll
        for (int g = 0; g < 4; ++g) {
            const float fbin = (float)(4 * w + 16 * half + g);   // f = 4*qf+g
            #pragma unroll
            for (int r = 0; r < 2; ++r) {
                const float t  = bstart + (fbin + (r ? 0.75f : 0.25f)) * binsz;
                const float wv = (t >= -1.0f && t <= (float)TT) ? 0.5f : 0.0f;
                float tc = fminf(fmaxf(t, 0.0f), (float)(TT - 1));
                int   lo = (int)tc;           // tc>=0: trunc==floor
                float fr = tc - (float)lo;
                // hi = lo+1 always valid: row TT duplicates TT-1
                const ushortv8 ulo = *(const ushortv8*)(base + (size_t)lo * CH);
                const ushortv8 uhi = *(const ushortv8*)(base + (size_t)(lo + 1) * CH);
                #pragma unroll
                for (int j = 0; j < 8; ++j) {
                    const float vl = __uint_as_float((unsigned)ulo[j] << 16);
                    const float vh = __uint_as_float((unsigned)uhi[j] << 16);
                    acc[g][j] += wv * (vl + fr * (vh - vl));
                }
            }
        }

        // ---- two-phase LDS transpose epilogue (16 KB), nt stores ----
        floatv4* ob = (floatv4*)(out + (size_t)m * (CH * 32));
        #pragma unroll
        for (int p = 0; p < 2; ++p) {
            if (p) __syncthreads();           // phase-0 reads done before rewrite
            if (half == p) {
                #pragma unroll
                for (int j = 0; j < 8; ++j) {
                    const int ch = 8 * lc + j;
                    floatv4 t4;
                    t4.x = acc[0][j]; t4.y = acc[1][j];
                    t4.z = acc[2][j]; t4.w = acc[3][j];
                    buf[ch >> 1][((ch & 1) * 4 + w) ^ (lc & 7)] = t4;
                }
            }
            __syncthreads();
            #pragma unroll
            for (int s = 0; s < 4; ++s) {
                const int ch  = 64 * w + 16 * s + (l >> 2);
                const int qfc = l & 3;        // absolute qf = 4p + qfc
                const floatv4 v =
                    buf[ch >> 1][((ch & 1) * 4 + qfc) ^ ((ch >> 3) & 7)];
                __builtin_nontemporal_store(v, &ob[(size_t)ch * 8 + 4 * p + qfc]);
            }
        }
    } else {
        // generic-ratio path: thread = channel, scalar bf16 taps
        const int c = tid;
        const float inv_ratio = 1.0f / (float)ratio;
        const unsigned short* base =
            (const unsigned short*)inT + (size_t)b * (TT + 1) * CH + c;
        for (int f = 0; f < 32; ++f) {
            float a = 0.0f;
            for (int r = 0; r < ratio; ++r) {
                const float off = (float)f + ((float)r + 0.5f) * inv_ratio;
                const float t   = bstart + off * binsz;
                if (t >= -1.0f && t <= (float)TT) {
                    float tc = fminf(fmaxf(t, 0.0f), (float)(TT - 1));
                    int   lo = (int)tc;
                    float fr = tc - (float)lo;
                    const float vl = __uint_as_float((unsigned)base[(size_t)lo * CH] << 16);
                    const float vh = __uint_as_float((unsigned)base[(size_t)(lo + 1) * CH] << 16);
                    a += vl * (1.0f - fr) + vh * fr;
                }
            }
            out[((size_t)m * CH + c) * 32 + f] = a * inv_ratio;
        }
    }
}

// ---------------------------------------------------------------------------
// Generic fallback (any fd, no transpose, reads original f32 layout).
// ---------------------------------------------------------------------------
__global__ __launch_bounds__(256) void ROIAlign_generic_kernel(
    const float* __restrict__ in,      // (BS, CH, TT)
    const float* __restrict__ rois,
    const int*   __restrict__ ratio_p,
    float*       __restrict__ out,     // (N, CH, fd)
    int fd)
{
    const int n = blockIdx.x;
    const int   ratio     = ratio_p[0];
    const float inv_ratio = 1.0f / (float)ratio;

    const int   b      = (int)rois[3 * n + 0];
    const float bstart = rois[3 * n + 1];
    const float bend   = rois[3 * n + 2];
    const float roi_len = fmaxf(bend - bstart, 1.0f);
    const float bin     = roi_len / (float)fd;

    const int total = CH * fd;
    for (int idx = threadIdx.x; idx < total; idx += blockDim.x) {
        const int c = idx / fd;
        const int f = idx % fd;
        const float* base = in + ((size_t)b * CH + c) * TT;
        float a = 0.0f;
        for (int r = 0; r < ratio; ++r) {
            const float off = (float)f + ((float)r + 0.5f) * inv_ratio;
            const float t   = bstart + off * bin;
            if (t >= -1.0f && t <= (float)TT) {
                float tc = fminf(fmaxf(t, 0.0f), (float)(TT - 1));
                int   lo = (int)tc;
                int   hi = min(lo + 1, TT - 1);
                float fr = tc - (float)lo;
                a += base[lo] * (1.0f - fr) + base[hi] * fr;
            }
        }
        out[(size_t)n * total + idx] = a * inv_ratio;
    }
}

extern "C" void kernel_launch(void* const* d_in, const int* in_sizes, int n_in,
                              void* d_out, int out_size, void* d_ws, size_t ws_size,
                              hipStream_t stream) {
    const float* in      = (const float*)d_in[0];
    const float* rois    = (const float*)d_in[1];
    const int*   ratio_p = (const int*)d_in[3];
    float*       out     = (float*)d_out;

    const int N  = in_sizes[1] / 3;
    const int fd = out_size / (N * CH);
    const size_t transpose_bytes = (size_t)BS * (TT + 1) * CH * sizeof(__hip_bfloat16);
    const size_t perm_bytes      = (size_t)N * sizeof(int);

    const bool fast = (fd == 32) &&
                      (ws_size >= transpose_bytes + perm_bytes) &&
                      (in_sizes[0] == BS * CH * TT);

    if (fast) {
        __hip_bfloat16* inT = (__hip_bfloat16*)d_ws;
        const bool sorted = (N % 8 == 0) && (N <= 1 << 20);
        int* perm = sorted ? (int*)((char*)d_ws + transpose_bytes) : nullptr;

        dim3 tg(TT / 64, CH / 64, BS + (sorted ? 1 : 0));
        hipLaunchKernelGGL(ROIAlign_transpose_sort_kernel, tg, dim3(256), 0, stream,
                           in, inT, rois, N, perm);
        hipLaunchKernelGGL(ROIAlign_fd32_kernel, dim3(N), dim3(256), 0, stream,
                           inT, rois, ratio_p, perm, out);
    } else {
        hipLaunchKernelGGL(ROIAlign_generic_kernel, dim3(N), dim3(256), 0, stream,
                           in, rois, ratio_p, out, fd);
    }
}

// Round 10
// 47.617 us; speedup vs baseline: 1.4321x; 1.4321x over previous
//
#include <hip/hip_runtime.h>
#include <hip/hip_bf16.h>

#define BS 16
#define CH 256
#define TT 2048
#define NBINS 512   // 16 batches x 32 start-buckets

typedef unsigned short ushortv8 __attribute__((ext_vector_type(8)));

// ---------------------------------------------------------------------------
// Sort body: bin ROIs by (batch, start-bucket). 256 threads, one block.
// Within-bin order is atomic-arrival (nondeterministic) but each ROI's output
// is order-independent -> d_out deterministic.
// ---------------------------------------------------------------------------
__device__ void ROIAlign_sort_body(const float* __restrict__ rois, int N,
                                   int* __restrict__ perm, int tid)
{
    __shared__ int hist[NBINS];
    __shared__ int waveSums[4];

    for (int i = tid; i < NBINS; i += 256) hist[i] = 0;
    __syncthreads();

    for (int n = tid; n < N; n += 256) {
        const int   b  = (int)rois[3 * n];
        const float s  = rois[3 * n + 1];
        const int   sb = min(31, max(0, (int)(s * (1.0f / 64.0f))));  // TT/32=64
        atomicAdd(&hist[b * 32 + sb], 1);
    }
    __syncthreads();

    const int a0  = hist[2 * tid];
    const int a1  = hist[2 * tid + 1];
    const int own = a0 + a1;
    int v = own;
    #pragma unroll
    for (int d = 1; d < 64; d <<= 1) {
        int u = __shfl_up(v, d, 64);
        if ((tid & 63) >= d) v += u;
    }
    if ((tid & 63) == 63) waveSums[tid >> 6] = v;
    __syncthreads();
    if (tid == 0) {
        int run = 0;
        #pragma unroll
        for (int i = 0; i < 4; ++i) { int c = waveSums[i]; waveSums[i] = run; run += c; }
    }
    __syncthreads();
    const int excl = v - own + waveSums[tid >> 6];
    hist[2 * tid]     = excl;
    hist[2 * tid + 1] = excl + a0;
    __syncthreads();

    for (int n = tid; n < N; n += 256) {
        const int   b  = (int)rois[3 * n];
        const float s  = rois[3 * n + 1];
        const int   sb = min(31, max(0, (int)(s * (1.0f / 64.0f))));
        const int pos = atomicAdd(&hist[b * 32 + sb], 1);
        perm[pos] = n;
    }
}

// ---------------------------------------------------------------------------
// Transpose (BS, CH, TT) f32 -> (BS, TT+1, CH) bf16 (row TT dups TT-1).
// 64t x 64c tile, float4 normal loads (R9 falsified nt: bypassing L2 write-
// combine cost +20us; normal cache path is the efficient one), ushort8
// stores. LDS tile[64][65]: all phases <=2-way. Sort at blockIdx.z==BS.
// ---------------------------------------------------------------------------
__global__ __launch_bounds__(256) void ROIAlign_transpose_sort_kernel(
    const float* __restrict__ in, __hip_bfloat16* __restrict__ outT,
    const float* __restrict__ rois, int N, int* __restrict__ perm)
{
    const int tid = threadIdx.x;

    if (blockIdx.z == BS) {
        if (blockIdx.x == 0 && blockIdx.y == 0 && perm)
            ROIAlign_sort_body(rois, N, perm, tid);
        return;
    }

    __shared__ float tile[64][65];   // [c][t], odd row stride: <=2-way banks
    const int b  = blockIdx.z;
    const int t0 = blockIdx.x * 64;
    const int c0 = blockIdx.y * 64;

    // read: thread -> c-row r = tid>>2, t-chunk q = tid&3 (16 floats via 4xfloat4)
    {
        const int r = tid >> 2;
        const int q = tid & 3;
        const float* p = in + ((size_t)(b * CH + c0 + r)) * TT + t0 + q * 16;
        #pragma unroll
        for (int i = 0; i < 4; ++i) {
            const float4 f4 = *(const float4*)(p + 4 * i);
            tile[r][q * 16 + 4 * i + 0] = f4.x;
            tile[r][q * 16 + 4 * i + 1] = f4.y;
            tile[r][q * 16 + 4 * i + 2] = f4.z;
            tile[r][q * 16 + 4 * i + 3] = f4.w;
        }
    }
    __syncthreads();

    // write: thread -> ch-oct o = tid&7, t-row rr = tid>>3 (+32 per pass)
    {
        const int o  = tid & 7;
        const int rr = tid >> 3;
        #pragma unroll
        for (int p2 = 0; p2 < 2; ++p2) {
            const int rp = rr + 32 * p2;
            ushortv8 u;
            #pragma unroll
            for (int k = 0; k < 8; ++k)
                u[k] = __bfloat16_as_ushort(__float2bfloat16(tile[8 * o + k][rp]));
            *(ushortv8*)((unsigned short*)outT +
                ((size_t)b * (TT + 1) + t0 + rp) * CH + c0 + 8 * o) = u;
            if (t0 == TT - 64 && rp == 63) {      // pad row TT = dup of TT-1
                *(ushortv8*)((unsigned short*)outT +
                    ((size_t)b * (TT + 1) + TT) * CH + c0 + 8 * o) = u;
            }
        }
    }
}

// ---------------------------------------------------------------------------
// Main kernel, fd==32, ratio==2 fast path, bf16 gather rows (512B each).
// Thread (wave w, half, lane lc) owns bins f = 4*qf+g, qf = w + 4*half,
// channels 8lc..8lc+7. Gather: one 64-lane ushort8 load covers two 512B rows.
// Two-phase 16KB LDS transpose epilogue -> 8 blocks/CU, then NORMAL float4
// stores (1KB contiguous per wave-store; L2 write-combine -> efficient 64B
// dirty evictions; R9 proved nt stores cost +20us).
// ---------------------------------------------------------------------------
__global__ __launch_bounds__(256) void ROIAlign_fd32_kernel(
    const __hip_bfloat16* __restrict__ inT,   // (BS, TT+1, CH) bf16
    const float* __restrict__ rois,           // (N, 3)
    const int*   __restrict__ ratio_p,
    const int*   __restrict__ perm,           // may be null
    float*       __restrict__ out)            // (N, CH, 32) f32
{
    __shared__ float4 buf[128][8];            // 16 KB

    int m;
    if (perm) {
        const int chunk = gridDim.x >> 3;     // XCD-contiguous mapping
        const int sidx  = (blockIdx.x & 7) * chunk + (blockIdx.x >> 3);
        m = perm[sidx];
    } else {
        m = blockIdx.x;
    }
    const int tid = threadIdx.x;

    const int   b      = (int)rois[3 * m + 0];
    const float bstart = rois[3 * m + 1];
    const float bend   = rois[3 * m + 2];
    const float roi_len = fmaxf(bend - bstart, 1.0f);
    const float binsz   = roi_len * (1.0f / 32.0f);
    const int   ratio   = ratio_p[0];

    if (ratio == 2) {
        const int w    = tid >> 6;            // wave
        const int l    = tid & 63;
        const int half = l >> 5;              // qf = w + 4*half
        const int lc   = l & 31;              // channels 8lc..8lc+7

        const unsigned short* base =
            (const unsigned short*)inT + (size_t)b * (TT + 1) * CH + 8 * lc;

        float acc[4][8];
        #pragma unroll
        for (int g = 0; g < 4; ++g)
            #pragma unroll
            for (int j = 0; j < 8; ++j) acc[g][j] = 0.0f;

        #pragma unroll
        for (int g = 0; g < 4; ++g) {
            const float fbin = (float)(4 * w + 16 * half + g);   // f = 4*qf+g
            #pragma unroll
            for (int r = 0; r < 2; ++r) {
                const float t  = bstart + (fbin + (r ? 0.75f : 0.25f)) * binsz;
                const float wv = (t >= -1.0f && t <= (float)TT) ? 0.5f : 0.0f;
                float tc = fminf(fmaxf(t, 0.0f), (float)(TT - 1));
                int   lo = (int)tc;           // tc>=0: trunc==floor
                float fr = tc - (float)lo;
                // hi = lo+1 always valid: row TT duplicates TT-1
                const ushortv8 ulo = *(const ushortv8*)(base + (size_t)lo * CH);
                const ushortv8 uhi = *(const ushortv8*)(base + (size_t)(lo + 1) * CH);
                #pragma unroll
                for (int j = 0; j < 8; ++j) {
                    const float vl = __uint_as_float((unsigned)ulo[j] << 16);
                    const float vh = __uint_as_float((unsigned)uhi[j] << 16);
                    acc[g][j] += wv * (vl + fr * (vh - vl));
                }
            }
        }

        // ---- two-phase LDS transpose epilogue (16 KB) ----
        float4* ob = (float4*)(out + (size_t)m * (CH * 32));
        #pragma unroll
        for (int p = 0; p < 2; ++p) {
            if (p) __syncthreads();           // phase-0 reads done before rewrite
            if (half == p) {
                #pragma unroll
                for (int j = 0; j < 8; ++j) {
                    const int ch = 8 * lc + j;
                    buf[ch >> 1][((ch & 1) * 4 + w) ^ (lc & 7)] =
                        make_float4(acc[0][j], acc[1][j], acc[2][j], acc[3][j]);
                }
            }
            __syncthreads();
            #pragma unroll
            for (int s = 0; s < 4; ++s) {
                const int ch  = 64 * w + 16 * s + (l >> 2);
                const int qfc = l & 3;        // absolute qf = 4p + qfc
                const float4 v =
                    buf[ch >> 1][((ch & 1) * 4 + qfc) ^ ((ch >> 3) & 7)];
                ob[(size_t)ch * 8 + 4 * p + qfc] = v;
            }
        }
    } else {
        // generic-ratio path: thread = channel, scalar bf16 taps
        const int c = tid;
        const float inv_ratio = 1.0f / (float)ratio;
        const unsigned short* base =
            (const unsigned short*)inT + (size_t)b * (TT + 1) * CH + c;
        for (int f = 0; f < 32; ++f) {
            float a = 0.0f;
            for (int r = 0; r < ratio; ++r) {
                const float off = (float)f + ((float)r + 0.5f) * inv_ratio;
                const float t   = bstart + off * binsz;
                if (t >= -1.0f && t <= (float)TT) {
                    float tc = fminf(fmaxf(t, 0.0f), (float)(TT - 1));
                    int   lo = (int)tc;
                    float fr = tc - (float)lo;
                    const float vl = __uint_as_float((unsigned)base[(size_t)lo * CH] << 16);
                    const float vh = __uint_as_float((unsigned)base[(size_t)(lo + 1) * CH] << 16);
                    a += vl * (1.0f - fr) + vh * fr;
                }
            }
            out[((size_t)m * CH + c) * 32 + f] = a * inv_ratio;
        }
    }
}

// ---------------------------------------------------------------------------
// Generic fallback (any fd, no transpose, reads original f32 layout).
// ---------------------------------------------------------------------------
__global__ __launch_bounds__(256) void ROIAlign_generic_kernel(
    const float* __restrict__ in,      // (BS, CH, TT)
    const float* __restrict__ rois,
    const int*   __restrict__ ratio_p,
    float*       __restrict__ out,     // (N, CH, fd)
    int fd)
{
    const int n = blockIdx.x;
    const int   ratio     = ratio_p[0];
    const float inv_ratio = 1.0f / (float)ratio;

    const int   b      = (int)rois[3 * n + 0];
    const float bstart = rois[3 * n + 1];
    const float bend   = rois[3 * n + 2];
    const float roi_len = fmaxf(bend - bstart, 1.0f);
    const float bin     = roi_len / (float)fd;

    const int total = CH * fd;
    for (int idx = threadIdx.x; idx < total; idx += blockDim.x) {
        const int c = idx / fd;
        const int f = idx % fd;
        const float* base = in + ((size_t)b * CH + c) * TT;
        float a = 0.0f;
        for (int r = 0; r < ratio; ++r) {
            const float off = (float)f + ((float)r + 0.5f) * inv_ratio;
            const float t   = bstart + off * bin;
            if (t >= -1.0f && t <= (float)TT) {
                float tc = fminf(fmaxf(t, 0.0f), (float)(TT - 1));
                int   lo = (int)tc;
                int   hi = min(lo + 1, TT - 1);
                float fr = tc - (float)lo;
                a += base[lo] * (1.0f - fr) + base[hi] * fr;
            }
        }
        out[(size_t)n * total + idx] = a * inv_ratio;
    }
}

extern "C" void kernel_launch(void* const* d_in, const int* in_sizes, int n_in,
                              void* d_out, int out_size, void* d_ws, size_t ws_size,
                              hipStream_t stream) {
    const float* in      = (const float*)d_in[0];
    const float* rois    = (const float*)d_in[1];
    const int*   ratio_p = (const int*)d_in[3];
    float*       out     = (float*)d_out;

    const int N  = in_sizes[1] / 3;
    const int fd = out_size / (N * CH);
    const size_t transpose_bytes = (size_t)BS * (TT + 1) * CH * sizeof(__hip_bfloat16);
    const size_t perm_bytes      = (size_t)N * sizeof(int);

    const bool fast = (fd == 32) &&
                      (ws_size >= transpose_bytes + perm_bytes) &&
                      (in_sizes[0] == BS * CH * TT);

    if (fast) {
        __hip_bfloat16* inT = (__hip_bfloat16*)d_ws;
        const bool sorted = (N % 8 == 0) && (N <= 1 << 20);
        int* perm = sorted ? (int*)((char*)d_ws + transpose_bytes) : nullptr;

        dim3 tg(TT / 64, CH / 64, BS + (sorted ? 1 : 0));
        hipLaunchKernelGGL(ROIAlign_transpose_sort_kernel, tg, dim3(256), 0, stream,
                           in, inT, rois, N, perm);
        hipLaunchKernelGGL(ROIAlign_fd32_kernel, dim3(N), dim3(256), 0, stream,
                           inT, rois, ratio_p, perm, out);
    } else {
        hipLaunchKernelGGL(ROIAlign_generic_kernel, dim3(N), dim3(256), 0, stream,
                           in, rois, ratio_p, out, fd);
    }
}